// Round 3
// baseline (2097.421 us; speedup 1.0000x reference)
//
#include <hip/hip_runtime.h>
#include <hip/hip_bf16.h>

#define N_NODESC 100000
#define N_EDGESC 1600000
#define N_GRAPHSC 200
#define IN_DIMC 25
#define HIDC 256
#define OUT_DIMC 128

// ---------- bf16 helpers (raw ushort storage) ----------
__device__ inline float bf2f(unsigned short u) {
    union { float f; unsigned u32; } c;
    c.u32 = ((unsigned)u) << 16;
    return c.f;
}
__device__ inline unsigned short f2bf(float f) {
    union { float f; unsigned u; } c;
    c.f = f;
    unsigned r = (c.u + 0x7FFFu + ((c.u >> 16) & 1u)) >> 16;  // RNE
    return (unsigned short)r;
}

// ---------- utility fills (no hipMemsetAsync inside capture) ----------
__global__ void fill_u32(unsigned* __restrict__ p, unsigned v, int n) {
    int i = blockIdx.x * 256 + threadIdx.x;
    if (i < n) p[i] = v;
}

// ---------- degree / inv ----------
__global__ void deg_kernel(const int* __restrict__ dst, int* __restrict__ cnt, int E) {
    int i = blockIdx.x * 256 + threadIdx.x;
    if (i < E) atomicAdd(&cnt[dst[i]], 1);
}
__global__ void inv_kernel(const int* __restrict__ cnt, float* __restrict__ inv, int n) {
    int i = blockIdx.x * 256 + threadIdx.x;
    if (i < n) inv[i] = 1.0f / (float)max(cnt[i], 1);
}

// ---------- single-block exclusive scan over N_NODES counts ----------
__global__ __launch_bounds__(1024) void scan_kernel(const int* __restrict__ cnt,
                                                    int* __restrict__ ofs) {
    __shared__ int sm[1024];
    __shared__ int carry;
    const int tid = threadIdx.x;
    if (tid == 0) carry = 0;
    __syncthreads();
    for (int base = 0; base < N_NODESC; base += 1024) {
        int i = base + tid;
        int v = (i < N_NODESC) ? cnt[i] : 0;
        sm[tid] = v;
        __syncthreads();
        for (int off = 1; off < 1024; off <<= 1) {
            int t = (tid >= off) ? sm[tid - off] : 0;
            __syncthreads();
            sm[tid] += t;
            __syncthreads();
        }
        int incl = sm[tid];
        int c0 = carry;
        if (i < N_NODESC) ofs[i] = c0 + incl - v;
        __syncthreads();
        if (tid == 0) carry += sm[1023];
        __syncthreads();
    }
    if (tid == 0) ofs[N_NODESC] = carry;
}

// ---------- CSR fill (counting sort by dst) ----------
__global__ void csr_fill(const int* __restrict__ src, const int* __restrict__ dst,
                         const int* __restrict__ ofs, int* __restrict__ cursor,
                         int* __restrict__ csr, int E) {
    int e = blockIdx.x * 256 + threadIdx.x;
    if (e < E) {
        int d = dst[e];
        int pos = atomicAdd(&cursor[d], 1);
        csr[ofs[d] + pos] = src[e];
    }
}

// ---------- graph ranges (batch sorted) ----------
__global__ void ranges_kernel(const int* __restrict__ batch, int* __restrict__ gstart,
                              int* __restrict__ gend, int n) {
    int i = blockIdx.x * 256 + threadIdx.x;
    if (i < n) {
        int g = batch[i];
        atomicMin(&gstart[g], i);
        atomicMax(&gend[g], i + 1);
    }
}

// ---------- layer-1 mean gather (f32, 25 channels) ----------
__global__ void gather25(const float* __restrict__ x, const int* __restrict__ ofs,
                         const int* __restrict__ csr, const float* __restrict__ inv,
                         float* __restrict__ agg) {
    int idx = blockIdx.x * 256 + threadIdx.x;
    int node = idx >> 5, c = idx & 31;
    if (node >= N_NODESC || c >= IN_DIMC) return;
    float acc = 0.0f;
    int s = ofs[node], e = ofs[node + 1];
    for (int j = s; j < e; ++j) acc += x[(size_t)csr[j] * IN_DIMC + c];
    agg[(size_t)node * IN_DIMC + c] = acc * inv[node];
}

// ---------- hidden mean gather (bf16 rows, one wave per node) ----------
__global__ void gather256(const unsigned short* __restrict__ h, const int* __restrict__ ofs,
                          const int* __restrict__ csr, const float* __restrict__ inv,
                          unsigned short* __restrict__ agg) {
    int wid = (int)(((long long)blockIdx.x * 256 + threadIdx.x) >> 6);
    int lane = threadIdx.x & 63;
    if (wid >= N_NODESC) return;
    float a0 = 0, a1 = 0, a2 = 0, a3 = 0;
    int s = ofs[wid], e = ofs[wid + 1];
    for (int j = s; j < e; ++j) {
        int sn = csr[j];
        ushort4 v = *reinterpret_cast<const ushort4*>(h + (size_t)sn * HIDC + lane * 4);
        a0 += bf2f(v.x); a1 += bf2f(v.y); a2 += bf2f(v.z); a3 += bf2f(v.w);
    }
    float sc = inv[wid];
    ushort4 o;
    o.x = f2bf(a0 * sc); o.y = f2bf(a1 * sc); o.z = f2bf(a2 * sc); o.w = f2bf(a3 * sc);
    *reinterpret_cast<ushort4*>(agg + (size_t)wid * HIDC + lane * 4) = o;
}

// ---------- fused SAGE GEMM: out = relu(agg @ Wl + h @ Wr + b), bf16 out ----------
// agg rows are ALREADY means (gathers apply 1/deg). BM=64,BN=64,BK=16; 4x4 microtile.
template <int K, bool ABF>
__global__ __launch_bounds__(256) void sage_gemm(
    const void* __restrict__ aggv, const void* __restrict__ hv,
    const float* __restrict__ Wl, const float* __restrict__ Wr,
    const float* __restrict__ bias,
    unsigned short* __restrict__ out, int nrows) {
    constexpr int BM = 64, BN = 64, BK = 16;
    __shared__ float sA[BK][BM + 4];
    __shared__ float sB[BK][BN + 4];
    const int tid = threadIdx.x;
    const int tx = tid & 15, ty = tid >> 4;
    const int rowbase = blockIdx.x * BM;
    const int colbase = blockIdx.y * BN;
    float acc[4][4] = {};
    const int lrow = tid >> 2, lkq = (tid & 3) * 4;
    const int lkB = tid >> 4, lnB = (tid & 15) * 4;

    for (int pass = 0; pass < 2; ++pass) {
        const void* __restrict__ A = pass ? hv : aggv;
        const float* __restrict__ W = pass ? Wr : Wl;
        const int grow = rowbase + lrow;
        for (int kb = 0; kb < K; kb += BK) {
#pragma unroll
            for (int j = 0; j < 4; ++j) {
                int k = kb + lkq + j;
                float v = 0.0f;
                if (grow < nrows && k < K) {
                    if (ABF)
                        v = bf2f(((const unsigned short*)A)[(size_t)grow * K + k]);
                    else
                        v = ((const float*)A)[(size_t)grow * K + k];
                }
                sA[lkq + j][lrow] = v;
            }
#pragma unroll
            for (int j = 0; j < 4; ++j) {
                int k = kb + lkB;
                int n = colbase + lnB + j;
                sB[lkB][lnB + j] = (k < K) ? W[(size_t)k * HIDC + n] : 0.0f;
            }
            __syncthreads();
#pragma unroll
            for (int kk = 0; kk < BK; ++kk) {
                float a[4], b[4];
#pragma unroll
                for (int i = 0; i < 4; ++i) a[i] = sA[kk][ty * 4 + i];
#pragma unroll
                for (int j = 0; j < 4; ++j) b[j] = sB[kk][tx * 4 + j];
#pragma unroll
                for (int i = 0; i < 4; ++i)
#pragma unroll
                    for (int j = 0; j < 4; ++j) acc[i][j] += a[i] * b[j];
            }
            __syncthreads();
        }
    }
#pragma unroll
    for (int i = 0; i < 4; ++i) {
        int r = rowbase + ty * 4 + i;
        if (r >= nrows) continue;
#pragma unroll
        for (int j = 0; j < 4; ++j) {
            int c = colbase + tx * 4 + j;
            out[(size_t)r * HIDC + c] = f2bf(fmaxf(acc[i][j] + bias[c], 0.0f));
        }
    }
}

// ---------- segment-max pool over contiguous node ranges ----------
__global__ void pool_max(const unsigned short* __restrict__ h, const int* __restrict__ gstart,
                         const int* __restrict__ gend, float* __restrict__ xc, int col_off) {
    int g = blockIdx.x;
    int c = threadIdx.x;
    float m = 0.0f;  // relu outputs >= 0
    int s = gstart[g], e = gend[g];
    for (int i = s; i < e; ++i) m = fmaxf(m, bf2f(h[(size_t)i * HIDC + c]));
    xc[(size_t)g * (3 * HIDC) + col_off + c] = m;
}

// ---------- head MLPs ----------
__global__ void mlp1(const float* __restrict__ xc, const float* __restrict__ W,
                     const float* __restrict__ b, float* __restrict__ hmid) {
    __shared__ float row[3 * HIDC];
    int g = blockIdx.x;
    for (int i = threadIdx.x; i < 3 * HIDC; i += 256) row[i] = xc[(size_t)g * (3 * HIDC) + i];
    __syncthreads();
    float acc = b[threadIdx.x];
    for (int k = 0; k < 3 * HIDC; ++k) acc += row[k] * W[(size_t)k * HIDC + threadIdx.x];
    hmid[(size_t)g * HIDC + threadIdx.x] = fmaxf(acc, 0.0f);
}

__global__ void mlp2(const float* __restrict__ hmid, const float* __restrict__ W,
                     const float* __restrict__ b, float* __restrict__ out) {
    __shared__ float row[HIDC];
    int g = blockIdx.x;
    for (int i = threadIdx.x; i < HIDC; i += 128) row[i] = hmid[(size_t)g * HIDC + i];
    __syncthreads();
    float acc = b[threadIdx.x];
    for (int k = 0; k < HIDC; ++k) acc += row[k] * W[(size_t)k * OUT_DIMC + threadIdx.x];
    out[(size_t)g * OUT_DIMC + threadIdx.x] = acc;
}

static inline char* align_up(char* p, size_t a) {
    return (char*)(((uintptr_t)p + a - 1) & ~(uintptr_t)(a - 1));
}

extern "C" void kernel_launch(void* const* d_in, const int* in_sizes, int n_in,
                              void* d_out, int out_size, void* d_ws, size_t ws_size,
                              hipStream_t stream) {
    const float* x = (const float*)d_in[0];
    const int* edge_index = (const int*)d_in[1];
    const int* batch = (const int*)d_in[2];
    const float* W1l = (const float*)d_in[3];
    const float* W1r = (const float*)d_in[4];
    const float* b1 = (const float*)d_in[5];
    const float* W2l = (const float*)d_in[6];
    const float* W2r = (const float*)d_in[7];
    const float* b2 = (const float*)d_in[8];
    const float* W3l = (const float*)d_in[9];
    const float* W3r = (const float*)d_in[10];
    const float* b3 = (const float*)d_in[11];
    const float* Wlin1 = (const float*)d_in[12];
    const float* blin1 = (const float*)d_in[13];
    const float* Wlin2 = (const float*)d_in[14];
    const float* blin2 = (const float*)d_in[15];
    float* out = (float*)d_out;

    const int N = N_NODESC, E = N_EDGESC;
    const int* src = edge_index;
    const int* dst = edge_index + E;

    // ---- workspace carve-up (~162 MB) ----
    char* w0 = (char*)d_ws;
    char* w = w0;
    int* cnt = (int*)w;        w = align_up(w + (size_t)N * 4, 256);
    float* invc = (float*)w;   w = align_up(w + (size_t)N * 4, 256);
    int* row_ofs = (int*)w;    w = align_up(w + (size_t)(N + 1) * 4, 256);
    int* csr = (int*)w;        w = align_up(w + (size_t)E * 4, 256);
    int* gstart = (int*)w;     w = align_up(w + (size_t)N_GRAPHSC * 4, 256);
    int* gend = (int*)w;       w = align_up(w + (size_t)N_GRAPHSC * 4, 256);
    float* xc = (float*)w;     w = align_up(w + (size_t)N_GRAPHSC * 3 * HIDC * 4, 256);
    float* hmid = (float*)w;   w = align_up(w + (size_t)N_GRAPHSC * HIDC * 4, 256);
    // aggU: union of layer-1 f32 agg (N*25*4 = 10 MB) and bf16 agg (N*256*2 = 51.2 MB)
    char* aggU = w;            w = align_up(w + (size_t)N * HIDC * 2, 256);
    unsigned short* h1 = (unsigned short*)w;  w = align_up(w + (size_t)N * HIDC * 2, 256);
    unsigned short* h2 = (unsigned short*)w;  w = align_up(w + (size_t)N * HIDC * 2, 256);
    size_t required = (size_t)(w - w0);
    if (ws_size < required) return;  // diagnostic: clean absmax fail (~3.797) => ws too small

    float* agg25 = (float*)aggU;
    unsigned short* aggH = (unsigned short*)aggU;

    const int nbN = (N + 255) / 256;
    const int nbE = (E + 255) / 256;
    const dim3 gemm_grid((N + 63) / 64, HIDC / 64);

    // degrees + inv
    fill_u32<<<nbN, 256, 0, stream>>>((unsigned*)cnt, 0u, N);
    deg_kernel<<<nbE, 256, 0, stream>>>(dst, cnt, E);
    inv_kernel<<<nbN, 256, 0, stream>>>(cnt, invc, N);
    // CSR
    scan_kernel<<<1, 1024, 0, stream>>>(cnt, row_ofs);
    fill_u32<<<nbN, 256, 0, stream>>>((unsigned*)cnt, 0u, N);  // cnt -> cursor
    csr_fill<<<nbE, 256, 0, stream>>>(src, dst, row_ofs, cnt, csr, E);
    // graph ranges
    fill_u32<<<1, 256, 0, stream>>>((unsigned*)gstart, (unsigned)N, N_GRAPHSC);
    fill_u32<<<1, 256, 0, stream>>>((unsigned*)gend, 0u, N_GRAPHSC);
    ranges_kernel<<<nbN, 256, 0, stream>>>(batch, gstart, gend, N);

    // ---- layer 1 (K=25, f32 in, bf16 out) ----
    gather25<<<(N * 32 + 255) / 256, 256, 0, stream>>>(x, row_ofs, csr, invc, agg25);
    sage_gemm<IN_DIMC, false><<<gemm_grid, 256, 0, stream>>>(agg25, x, W1l, W1r, b1, h1, N);
    pool_max<<<N_GRAPHSC, 256, 0, stream>>>(h1, gstart, gend, xc, 0);

    // ---- layer 2 ----
    gather256<<<(N * 64 + 255) / 256, 256, 0, stream>>>(h1, row_ofs, csr, invc, aggH);
    sage_gemm<HIDC, true><<<gemm_grid, 256, 0, stream>>>(aggH, h1, W2l, W2r, b2, h2, N);
    pool_max<<<N_GRAPHSC, 256, 0, stream>>>(h2, gstart, gend, xc, HIDC);

    // ---- layer 3 (output reuses h1's buffer; h1 dead by now) ----
    gather256<<<(N * 64 + 255) / 256, 256, 0, stream>>>(h2, row_ofs, csr, invc, aggH);
    sage_gemm<HIDC, true><<<gemm_grid, 256, 0, stream>>>(aggH, h2, W3l, W3r, b3, h1, N);
    pool_max<<<N_GRAPHSC, 256, 0, stream>>>(h1, gstart, gend, xc, 2 * HIDC);

    // ---- head ----
    mlp1<<<N_GRAPHSC, 256, 0, stream>>>(xc, Wlin1, blin1, hmid);
    mlp2<<<N_GRAPHSC, 128, 0, stream>>>(hmid, Wlin2, blin2, out);
}

// Round 4
// 1588.531 us; speedup vs baseline: 1.3204x; 1.3204x over previous
//
#include <hip/hip_runtime.h>
#include <hip/hip_bf16.h>

#define N_NODESC 100000
#define N_EDGESC 1600000
#define N_GRAPHSC 200
#define IN_DIMC 25
#define HIDC 256
#define OUT_DIMC 128

typedef __attribute__((ext_vector_type(8))) short bf16x8;
typedef __attribute__((ext_vector_type(4))) float f32x4;

// ---------- bf16 helpers (raw ushort storage) ----------
__device__ inline float bf2f(unsigned short u) {
    union { float f; unsigned u32; } c;
    c.u32 = ((unsigned)u) << 16;
    return c.f;
}
__device__ inline unsigned short f2bf(float f) {
    union { float f; unsigned u; } c;
    c.f = f;
    unsigned r = (c.u + 0x7FFFu + ((c.u >> 16) & 1u)) >> 16;  // RNE
    return (unsigned short)r;
}

// ---------- utility fills ----------
__global__ void fill_u32(unsigned* __restrict__ p, unsigned v, int n) {
    int i = blockIdx.x * 256 + threadIdx.x;
    if (i < n) p[i] = v;
}

// ---------- degree / inv ----------
__global__ void deg_kernel(const int* __restrict__ dst, int* __restrict__ cnt, int E) {
    int i = blockIdx.x * 256 + threadIdx.x;
    if (i < E) atomicAdd(&cnt[dst[i]], 1);
}
__global__ void inv_kernel(const int* __restrict__ cnt, float* __restrict__ inv, int n) {
    int i = blockIdx.x * 256 + threadIdx.x;
    if (i < n) inv[i] = 1.0f / (float)max(cnt[i], 1);
}

// ---------- single-block exclusive scan ----------
__global__ __launch_bounds__(1024) void scan_kernel(const int* __restrict__ cnt,
                                                    int* __restrict__ ofs) {
    __shared__ int sm[1024];
    __shared__ int carry;
    const int tid = threadIdx.x;
    if (tid == 0) carry = 0;
    __syncthreads();
    for (int base = 0; base < N_NODESC; base += 1024) {
        int i = base + tid;
        int v = (i < N_NODESC) ? cnt[i] : 0;
        sm[tid] = v;
        __syncthreads();
        for (int off = 1; off < 1024; off <<= 1) {
            int t = (tid >= off) ? sm[tid - off] : 0;
            __syncthreads();
            sm[tid] += t;
            __syncthreads();
        }
        int incl = sm[tid];
        int c0 = carry;
        if (i < N_NODESC) ofs[i] = c0 + incl - v;
        __syncthreads();
        if (tid == 0) carry += sm[1023];
        __syncthreads();
    }
    if (tid == 0) ofs[N_NODESC] = carry;
}

// ---------- CSR fill ----------
__global__ void csr_fill(const int* __restrict__ src, const int* __restrict__ dst,
                         const int* __restrict__ ofs, int* __restrict__ cursor,
                         int* __restrict__ csr, int E) {
    int e = blockIdx.x * 256 + threadIdx.x;
    if (e < E) {
        int d = dst[e];
        int pos = atomicAdd(&cursor[d], 1);
        csr[ofs[d] + pos] = src[e];
    }
}

// ---------- graph ranges ----------
__global__ void ranges_kernel(const int* __restrict__ batch, int* __restrict__ gstart,
                              int* __restrict__ gend, int n) {
    int i = blockIdx.x * 256 + threadIdx.x;
    if (i < n) {
        int g = batch[i];
        atomicMin(&gstart[g], i);
        atomicMax(&gend[g], i + 1);
    }
}

// ---------- weight transpose f32[256][256] -> bf16 WT[n][k] ----------
__global__ void wtransT(const float* __restrict__ W, unsigned short* __restrict__ WT) {
    __shared__ float t[16][17];
    int bx = blockIdx.x, by = blockIdx.y;
    int tx = threadIdx.x & 15, ty = threadIdx.x >> 4;
    t[ty][tx] = W[(by * 16 + ty) * HIDC + bx * 16 + tx];
    __syncthreads();
    WT[(size_t)(bx * 16 + ty) * HIDC + by * 16 + tx] = f2bf(t[tx][ty]);
}

// ---------- layer-1 mean gather (f32, 25 channels) ----------
__global__ void gather25(const float* __restrict__ x, const int* __restrict__ ofs,
                         const int* __restrict__ csr, const float* __restrict__ inv,
                         float* __restrict__ agg) {
    int idx = blockIdx.x * 256 + threadIdx.x;
    int node = idx >> 5, c = idx & 31;
    if (node >= N_NODESC || c >= IN_DIMC) return;
    float acc = 0.0f;
    int s = ofs[node], e = ofs[node + 1];
    for (int j = s; j < e; ++j) acc += x[(size_t)csr[j] * IN_DIMC + c];
    agg[(size_t)node * IN_DIMC + c] = acc * inv[node];
}

// ---------- hidden mean gather (bf16 rows, one wave per node) ----------
__global__ void gather256(const unsigned short* __restrict__ h, const int* __restrict__ ofs,
                          const int* __restrict__ csr, const float* __restrict__ inv,
                          unsigned short* __restrict__ agg) {
    int wid = (int)(((long long)blockIdx.x * 256 + threadIdx.x) >> 6);
    int lane = threadIdx.x & 63;
    if (wid >= N_NODESC) return;
    float a0 = 0, a1 = 0, a2 = 0, a3 = 0;
    int s = ofs[wid], e = ofs[wid + 1];
    for (int j = s; j < e; ++j) {
        int sn = csr[j];
        ushort4 v = *reinterpret_cast<const ushort4*>(h + (size_t)sn * HIDC + lane * 4);
        a0 += bf2f(v.x); a1 += bf2f(v.y); a2 += bf2f(v.z); a3 += bf2f(v.w);
    }
    float sc = inv[wid];
    ushort4 o;
    o.x = f2bf(a0 * sc); o.y = f2bf(a1 * sc); o.z = f2bf(a2 * sc); o.w = f2bf(a3 * sc);
    *reinterpret_cast<ushort4*>(agg + (size_t)wid * HIDC + lane * 4) = o;
}

// ---------- layer-1 f32 SAGE GEMM (K=25) ----------
template <int K>
__global__ __launch_bounds__(256) void sage_gemm_f32(
    const float* __restrict__ agg, const float* __restrict__ h,
    const float* __restrict__ Wl, const float* __restrict__ Wr,
    const float* __restrict__ bias,
    unsigned short* __restrict__ out, int nrows) {
    constexpr int BM = 64, BN = 64, BK = 16;
    __shared__ float sA[BK][BM + 4];
    __shared__ float sB[BK][BN + 4];
    const int tid = threadIdx.x;
    const int tx = tid & 15, ty = tid >> 4;
    const int rowbase = blockIdx.x * BM;
    const int colbase = blockIdx.y * BN;
    float acc[4][4] = {};
    const int lrow = tid >> 2, lkq = (tid & 3) * 4;
    const int lkB = tid >> 4, lnB = (tid & 15) * 4;

    for (int pass = 0; pass < 2; ++pass) {
        const float* __restrict__ A = pass ? h : agg;
        const float* __restrict__ W = pass ? Wr : Wl;
        const int grow = rowbase + lrow;
        for (int kb = 0; kb < K; kb += BK) {
#pragma unroll
            for (int j = 0; j < 4; ++j) {
                int k = kb + lkq + j;
                float v = 0.0f;
                if (grow < nrows && k < K) v = A[(size_t)grow * K + k];
                sA[lkq + j][lrow] = v;
            }
#pragma unroll
            for (int j = 0; j < 4; ++j) {
                int k = kb + lkB;
                int n = colbase + lnB + j;
                sB[lkB][lnB + j] = (k < K) ? W[(size_t)k * HIDC + n] : 0.0f;
            }
            __syncthreads();
#pragma unroll
            for (int kk = 0; kk < BK; ++kk) {
                float a[4], b[4];
#pragma unroll
                for (int i = 0; i < 4; ++i) a[i] = sA[kk][ty * 4 + i];
#pragma unroll
                for (int j = 0; j < 4; ++j) b[j] = sB[kk][tx * 4 + j];
#pragma unroll
                for (int i = 0; i < 4; ++i)
#pragma unroll
                    for (int j = 0; j < 4; ++j) acc[i][j] += a[i] * b[j];
            }
            __syncthreads();
        }
    }
#pragma unroll
    for (int i = 0; i < 4; ++i) {
        int r = rowbase + ty * 4 + i;
        if (r >= nrows) continue;
#pragma unroll
        for (int j = 0; j < 4; ++j) {
            int c = colbase + tx * 4 + j;
            out[(size_t)r * HIDC + c] = f2bf(fmaxf(acc[i][j] + bias[c], 0.0f));
        }
    }
}

// ---------- MFMA bf16 SAGE GEMM (layers 2/3): out = relu(A0@B0 + A1@B1 + b) ----------
// A0/A1: [M][256] bf16 row-major. B0T/B1T: [256 n][256 k] bf16 (transposed weights).
// BM=128, BN=128, BK=32; 4 waves (2x2), 64x64 per wave, 4x4 fragments of 16x16x32.
__global__ __launch_bounds__(256) void sage_gemm_mfma(
    const unsigned short* __restrict__ A0, const unsigned short* __restrict__ A1,
    const unsigned short* __restrict__ B0T, const unsigned short* __restrict__ B1T,
    const float* __restrict__ bias, unsigned short* __restrict__ out, int M) {
    constexpr int BM = 128, BK = 32, KD = 256, LDA = 40;  // LDA pad: 80B rows, 16B aligned
    __shared__ unsigned short sA[BM * LDA];
    __shared__ unsigned short sB[BM * LDA];
    const int tid = threadIdx.x;
    const int lane = tid & 63;
    const int wid = tid >> 6;
    const int wm = wid >> 1, wn = wid & 1;
    const int rowbase = blockIdx.x * BM, colbase = blockIdx.y * BM;

    const int fr = lane & 15;          // fragment row/col within 16
    const int kq8 = (lane >> 4) << 3;  // 0,8,16,24 : k-offset of this lane's 8 elems

    f32x4 acc[4][4] = {};

    for (int pass = 0; pass < 2; ++pass) {
        const unsigned short* __restrict__ A = pass ? A1 : A0;
        const unsigned short* __restrict__ BT = pass ? B1T : B0T;
        for (int kb = 0; kb < KD; kb += BK) {
            // stage to regs: 2 chunks of 16B each for A and B tiles
            int4 av[2], bv[2];
#pragma unroll
            for (int c = 0; c < 2; ++c) {
                int chunk = tid + (c << 8);
                int r = chunk >> 2, kq = (chunk & 3) << 3;
                int gr = rowbase + r;
                av[c] = (gr < M)
                            ? *reinterpret_cast<const int4*>(A + (size_t)gr * KD + kb + kq)
                            : make_int4(0, 0, 0, 0);
                bv[c] = *reinterpret_cast<const int4*>(BT + (size_t)(colbase + r) * KD + kb + kq);
            }
            __syncthreads();  // previous iter's frag reads done
#pragma unroll
            for (int c = 0; c < 2; ++c) {
                int chunk = tid + (c << 8);
                int r = chunk >> 2, kq = (chunk & 3) << 3;
                *reinterpret_cast<int4*>(sA + r * LDA + kq) = av[c];
                *reinterpret_cast<int4*>(sB + r * LDA + kq) = bv[c];
            }
            __syncthreads();
            bf16x8 af[4], bfr[4];
#pragma unroll
            for (int t = 0; t < 4; ++t) {
                af[t] = *reinterpret_cast<const bf16x8*>(sA + (wm * 64 + t * 16 + fr) * LDA + kq8);
                bfr[t] = *reinterpret_cast<const bf16x8*>(sB + (wn * 64 + t * 16 + fr) * LDA + kq8);
            }
#pragma unroll
            for (int i = 0; i < 4; ++i)
#pragma unroll
                for (int j = 0; j < 4; ++j)
                    acc[i][j] = __builtin_amdgcn_mfma_f32_16x16x32_bf16(af[i], bfr[j], acc[i][j], 0, 0, 0);
        }
    }

    // epilogue: C/D layout col=lane&15, row=4*(lane>>4)+r
    const int crow0 = (lane >> 4) << 2;
#pragma unroll
    for (int i = 0; i < 4; ++i) {
#pragma unroll
        for (int j = 0; j < 4; ++j) {
            int col = colbase + wn * 64 + j * 16 + fr;
            float bb = bias[col];
#pragma unroll
            for (int r = 0; r < 4; ++r) {
                int row = rowbase + wm * 64 + i * 16 + crow0 + r;
                if (row < M)
                    out[(size_t)row * HIDC + col] = f2bf(fmaxf(acc[i][j][r] + bb, 0.0f));
            }
        }
    }
}

// ---------- segment-max pool ----------
__global__ void pool_max(const unsigned short* __restrict__ h, const int* __restrict__ gstart,
                         const int* __restrict__ gend, float* __restrict__ xc, int col_off) {
    int g = blockIdx.x;
    int c = threadIdx.x;
    float m = 0.0f;  // relu outputs >= 0
    int s = gstart[g], e = gend[g];
    for (int i = s; i < e; ++i) m = fmaxf(m, bf2f(h[(size_t)i * HIDC + c]));
    xc[(size_t)g * (3 * HIDC) + col_off + c] = m;
}

// ---------- head MLPs ----------
__global__ void mlp1(const float* __restrict__ xc, const float* __restrict__ W,
                     const float* __restrict__ b, float* __restrict__ hmid) {
    __shared__ float row[3 * HIDC];
    int g = blockIdx.x;
    for (int i = threadIdx.x; i < 3 * HIDC; i += 256) row[i] = xc[(size_t)g * (3 * HIDC) + i];
    __syncthreads();
    float acc = b[threadIdx.x];
    for (int k = 0; k < 3 * HIDC; ++k) acc += row[k] * W[(size_t)k * HIDC + threadIdx.x];
    hmid[(size_t)g * HIDC + threadIdx.x] = fmaxf(acc, 0.0f);
}

__global__ void mlp2(const float* __restrict__ hmid, const float* __restrict__ W,
                     const float* __restrict__ b, float* __restrict__ out) {
    __shared__ float row[HIDC];
    int g = blockIdx.x;
    for (int i = threadIdx.x; i < HIDC; i += 128) row[i] = hmid[(size_t)g * HIDC + i];
    __syncthreads();
    float acc = b[threadIdx.x];
    for (int k = 0; k < HIDC; ++k) acc += row[k] * W[(size_t)k * OUT_DIMC + threadIdx.x];
    out[(size_t)g * OUT_DIMC + threadIdx.x] = acc;
}

static inline char* align_up(char* p, size_t a) {
    return (char*)(((uintptr_t)p + a - 1) & ~(uintptr_t)(a - 1));
}

extern "C" void kernel_launch(void* const* d_in, const int* in_sizes, int n_in,
                              void* d_out, int out_size, void* d_ws, size_t ws_size,
                              hipStream_t stream) {
    const float* x = (const float*)d_in[0];
    const int* edge_index = (const int*)d_in[1];
    const int* batch = (const int*)d_in[2];
    const float* W1l = (const float*)d_in[3];
    const float* W1r = (const float*)d_in[4];
    const float* b1 = (const float*)d_in[5];
    const float* W2l = (const float*)d_in[6];
    const float* W2r = (const float*)d_in[7];
    const float* b2 = (const float*)d_in[8];
    const float* W3l = (const float*)d_in[9];
    const float* W3r = (const float*)d_in[10];
    const float* b3 = (const float*)d_in[11];
    const float* Wlin1 = (const float*)d_in[12];
    const float* blin1 = (const float*)d_in[13];
    const float* Wlin2 = (const float*)d_in[14];
    const float* blin2 = (const float*)d_in[15];
    float* out = (float*)d_out;

    const int N = N_NODESC, E = N_EDGESC;
    const int* src = edge_index;
    const int* dst = edge_index + E;

    // ---- workspace carve-up ----
    char* w0 = (char*)d_ws;
    char* w = w0;
    int* cnt = (int*)w;        w = align_up(w + (size_t)N * 4, 256);
    float* invc = (float*)w;   w = align_up(w + (size_t)N * 4, 256);
    int* row_ofs = (int*)w;    w = align_up(w + (size_t)(N + 1) * 4, 256);
    int* csr = (int*)w;        w = align_up(w + (size_t)E * 4, 256);
    int* gstart = (int*)w;     w = align_up(w + (size_t)N_GRAPHSC * 4, 256);
    int* gend = (int*)w;       w = align_up(w + (size_t)N_GRAPHSC * 4, 256);
    float* xc = (float*)w;     w = align_up(w + (size_t)N_GRAPHSC * 3 * HIDC * 4, 256);
    float* hmid = (float*)w;   w = align_up(w + (size_t)N_GRAPHSC * HIDC * 4, 256);
    unsigned short* W2lT = (unsigned short*)w; w = align_up(w + (size_t)HIDC * HIDC * 2, 256);
    unsigned short* W2rT = (unsigned short*)w; w = align_up(w + (size_t)HIDC * HIDC * 2, 256);
    unsigned short* W3lT = (unsigned short*)w; w = align_up(w + (size_t)HIDC * HIDC * 2, 256);
    unsigned short* W3rT = (unsigned short*)w; w = align_up(w + (size_t)HIDC * HIDC * 2, 256);
    char* aggU = w;            w = align_up(w + (size_t)N * HIDC * 2, 256);
    unsigned short* h1 = (unsigned short*)w;  w = align_up(w + (size_t)N * HIDC * 2, 256);
    unsigned short* h2 = (unsigned short*)w;  w = align_up(w + (size_t)N * HIDC * 2, 256);
    size_t required = (size_t)(w - w0);
    if (ws_size < required) return;

    float* agg25 = (float*)aggU;
    unsigned short* aggH = (unsigned short*)aggU;

    const int nbN = (N + 255) / 256;
    const int nbE = (E + 255) / 256;
    const dim3 gemm_grid_f32((N + 63) / 64, HIDC / 64);
    const dim3 gemm_grid_mfma((N + 127) / 128, HIDC / 128);
    const dim3 tgrid(16, 16);

    // weight transposes (independent)
    wtransT<<<tgrid, 256, 0, stream>>>(W2l, W2lT);
    wtransT<<<tgrid, 256, 0, stream>>>(W2r, W2rT);
    wtransT<<<tgrid, 256, 0, stream>>>(W3l, W3lT);
    wtransT<<<tgrid, 256, 0, stream>>>(W3r, W3rT);

    // degrees + inv
    fill_u32<<<nbN, 256, 0, stream>>>((unsigned*)cnt, 0u, N);
    deg_kernel<<<nbE, 256, 0, stream>>>(dst, cnt, E);
    inv_kernel<<<nbN, 256, 0, stream>>>(cnt, invc, N);
    // CSR
    scan_kernel<<<1, 1024, 0, stream>>>(cnt, row_ofs);
    fill_u32<<<nbN, 256, 0, stream>>>((unsigned*)cnt, 0u, N);
    csr_fill<<<nbE, 256, 0, stream>>>(src, dst, row_ofs, cnt, csr, E);
    // graph ranges
    fill_u32<<<1, 256, 0, stream>>>((unsigned*)gstart, (unsigned)N, N_GRAPHSC);
    fill_u32<<<1, 256, 0, stream>>>((unsigned*)gend, 0u, N_GRAPHSC);
    ranges_kernel<<<nbN, 256, 0, stream>>>(batch, gstart, gend, N);

    // ---- layer 1 (K=25, f32) ----
    gather25<<<(N * 32 + 255) / 256, 256, 0, stream>>>(x, row_ofs, csr, invc, agg25);
    sage_gemm_f32<IN_DIMC><<<gemm_grid_f32, 256, 0, stream>>>(agg25, x, W1l, W1r, b1, h1, N);
    pool_max<<<N_GRAPHSC, 256, 0, stream>>>(h1, gstart, gend, xc, 0);

    // ---- layer 2 (MFMA) ----
    gather256<<<(N * 64 + 255) / 256, 256, 0, stream>>>(h1, row_ofs, csr, invc, aggH);
    sage_gemm_mfma<<<gemm_grid_mfma, 256, 0, stream>>>(aggH, h1, W2lT, W2rT, b2, h2, N);
    pool_max<<<N_GRAPHSC, 256, 0, stream>>>(h2, gstart, gend, xc, HIDC);

    // ---- layer 3 (MFMA) ----
    gather256<<<(N * 64 + 255) / 256, 256, 0, stream>>>(h2, row_ofs, csr, invc, aggH);
    sage_gemm_mfma<<<gemm_grid_mfma, 256, 0, stream>>>(aggH, h2, W3lT, W3rT, b3, h1, N);
    pool_max<<<N_GRAPHSC, 256, 0, stream>>>(h1, gstart, gend, xc, 2 * HIDC);

    // ---- head ----
    mlp1<<<N_GRAPHSC, 256, 0, stream>>>(xc, Wlin1, blin1, hmid);
    mlp2<<<N_GRAPHSC, 128, 0, stream>>>(hmid, Wlin2, blin2, out);
}

// Round 5
// 1208.236 us; speedup vs baseline: 1.7359x; 1.3148x over previous
//
#include <hip/hip_runtime.h>
#include <hip/hip_bf16.h>

#define N_NODESC 100000
#define N_EDGESC 1600000
#define N_GRAPHSC 200
#define IN_DIMC 25
#define HIDC 256
#define OUT_DIMC 128
#define SCAN_BLK 1024
#define SCAN_NBLK ((N_NODESC + SCAN_BLK - 1) / SCAN_BLK)

typedef __attribute__((ext_vector_type(8))) short bf16x8;
typedef __attribute__((ext_vector_type(4))) float f32x4;

// ---------- bf16 helpers (raw ushort storage) ----------
__device__ inline float bf2f(unsigned short u) {
    union { float f; unsigned u32; } c;
    c.u32 = ((unsigned)u) << 16;
    return c.f;
}
__device__ inline unsigned short f2bf(float f) {
    union { float f; unsigned u; } c;
    c.f = f;
    unsigned r = (c.u + 0x7FFFu + ((c.u >> 16) & 1u)) >> 16;  // RNE
    return (unsigned short)r;
}

// ---------- utility fills ----------
__global__ void fill_u32(unsigned* __restrict__ p, unsigned v, int n) {
    int i = blockIdx.x * 256 + threadIdx.x;
    if (i < n) p[i] = v;
}

// ---------- degree / inv ----------
__global__ void deg_kernel(const int* __restrict__ dst, int* __restrict__ cnt, int E) {
    int i = blockIdx.x * 256 + threadIdx.x;
    if (i < E) atomicAdd(&cnt[dst[i]], 1);
}
__global__ void inv_kernel(const int* __restrict__ cnt, float* __restrict__ inv, int n) {
    int i = blockIdx.x * 256 + threadIdx.x;
    if (i < n) inv[i] = 1.0f / (float)max(cnt[i], 1);
}

// ---------- hierarchical exclusive scan over cnt[N] -> ofs[N+1] ----------
__global__ __launch_bounds__(SCAN_BLK) void scan_partial(const int* __restrict__ cnt,
                                                         int* __restrict__ ofs,
                                                         int* __restrict__ bsum) {
    __shared__ int sm[SCAN_BLK];
    int i = blockIdx.x * SCAN_BLK + threadIdx.x;
    int v = (i < N_NODESC) ? cnt[i] : 0;
    sm[threadIdx.x] = v;
    __syncthreads();
    for (int off = 1; off < SCAN_BLK; off <<= 1) {
        int t = (threadIdx.x >= off) ? sm[threadIdx.x - off] : 0;
        __syncthreads();
        sm[threadIdx.x] += t;
        __syncthreads();
    }
    if (i < N_NODESC) ofs[i] = sm[threadIdx.x] - v;  // exclusive within block
    if (threadIdx.x == SCAN_BLK - 1) bsum[blockIdx.x] = sm[SCAN_BLK - 1];
}

__global__ __launch_bounds__(128) void scan_bsums(int* __restrict__ bsum) {
    __shared__ int sm[SCAN_NBLK];
    if (threadIdx.x == 0) {
        int run = 0;
        for (int b = 0; b < SCAN_NBLK; ++b) {  // 98 elems, trivial serial
            int t = bsum[b];
            sm[b] = run;
            run += t;
        }
        for (int b = 0; b < SCAN_NBLK; ++b) bsum[b] = sm[b];
    }
}

__global__ __launch_bounds__(SCAN_BLK) void scan_add(int* __restrict__ ofs,
                                                     const int* __restrict__ bsum) {
    int i = blockIdx.x * SCAN_BLK + threadIdx.x;
    if (i < N_NODESC) ofs[i] += bsum[blockIdx.x];
    if (i == 0) ofs[N_NODESC] = N_EDGESC;  // total is always E
}

// ---------- CSR fill ----------
__global__ void csr_fill(const int* __restrict__ src, const int* __restrict__ dst,
                         const int* __restrict__ ofs, int* __restrict__ cursor,
                         int* __restrict__ csr, int E) {
    int e = blockIdx.x * 256 + threadIdx.x;
    if (e < E) {
        int d = dst[e];
        int pos = atomicAdd(&cursor[d], 1);
        csr[ofs[d] + pos] = src[e];
    }
}

// ---------- graph ranges: boundary scan (batch is sorted; no atomics) ----------
__global__ void ranges_bounds(const int* __restrict__ batch, int* __restrict__ gstart,
                              int* __restrict__ gend, int n) {
    int i = blockIdx.x * 256 + threadIdx.x;
    if (i >= n) return;
    int g = batch[i];
    if (i == 0 || batch[i - 1] != g) gstart[g] = i;
    if (i == n - 1 || batch[i + 1] != g) gend[g] = i + 1;
}

// ---------- weight transpose f32[256][256] -> bf16 WT[n][k] ----------
__global__ void wtransT(const float* __restrict__ W, unsigned short* __restrict__ WT) {
    __shared__ float t[16][17];
    int bx = blockIdx.x, by = blockIdx.y;
    int tx = threadIdx.x & 15, ty = threadIdx.x >> 4;
    t[ty][tx] = W[(by * 16 + ty) * HIDC + bx * 16 + tx];
    __syncthreads();
    WT[(size_t)(bx * 16 + ty) * HIDC + by * 16 + tx] = f2bf(t[tx][ty]);
}

// ---------- layer-1 mean gather (f32, 25 channels) ----------
__global__ void gather25(const float* __restrict__ x, const int* __restrict__ ofs,
                         const int* __restrict__ csr, const float* __restrict__ inv,
                         float* __restrict__ agg) {
    int idx = blockIdx.x * 256 + threadIdx.x;
    int node = idx >> 5, c = idx & 31;
    if (node >= N_NODESC || c >= IN_DIMC) return;
    float acc = 0.0f;
    int s = ofs[node], e = ofs[node + 1];
    for (int j = s; j < e; ++j) acc += x[(size_t)csr[j] * IN_DIMC + c];
    agg[(size_t)node * IN_DIMC + c] = acc * inv[node];
}

// ---------- hidden mean gather (bf16 rows, one wave per node) ----------
__global__ void gather256(const unsigned short* __restrict__ h, const int* __restrict__ ofs,
                          const int* __restrict__ csr, const float* __restrict__ inv,
                          unsigned short* __restrict__ agg) {
    int wid = (int)(((long long)blockIdx.x * 256 + threadIdx.x) >> 6);
    int lane = threadIdx.x & 63;
    if (wid >= N_NODESC) return;
    float a0 = 0, a1 = 0, a2 = 0, a3 = 0;
    int s = ofs[wid], e = ofs[wid + 1];
    for (int j = s; j < e; ++j) {
        int sn = csr[j];
        ushort4 v = *reinterpret_cast<const ushort4*>(h + (size_t)sn * HIDC + lane * 4);
        a0 += bf2f(v.x); a1 += bf2f(v.y); a2 += bf2f(v.z); a3 += bf2f(v.w);
    }
    float sc = inv[wid];
    ushort4 o;
    o.x = f2bf(a0 * sc); o.y = f2bf(a1 * sc); o.z = f2bf(a2 * sc); o.w = f2bf(a3 * sc);
    *reinterpret_cast<ushort4*>(agg + (size_t)wid * HIDC + lane * 4) = o;
}

// ---------- layer-1 f32 SAGE GEMM (K=25) ----------
template <int K>
__global__ __launch_bounds__(256) void sage_gemm_f32(
    const float* __restrict__ agg, const float* __restrict__ h,
    const float* __restrict__ Wl, const float* __restrict__ Wr,
    const float* __restrict__ bias,
    unsigned short* __restrict__ out, int nrows) {
    constexpr int BM = 64, BN = 64, BK = 16;
    __shared__ float sA[BK][BM + 4];
    __shared__ float sB[BK][BN + 4];
    const int tid = threadIdx.x;
    const int tx = tid & 15, ty = tid >> 4;
    const int rowbase = blockIdx.x * BM;
    const int colbase = blockIdx.y * BN;
    float acc[4][4] = {};
    const int lrow = tid >> 2, lkq = (tid & 3) * 4;
    const int lkB = tid >> 4, lnB = (tid & 15) * 4;

    for (int pass = 0; pass < 2; ++pass) {
        const float* __restrict__ A = pass ? h : agg;
        const float* __restrict__ W = pass ? Wr : Wl;
        const int grow = rowbase + lrow;
        for (int kb = 0; kb < K; kb += BK) {
#pragma unroll
            for (int j = 0; j < 4; ++j) {
                int k = kb + lkq + j;
                float v = 0.0f;
                if (grow < nrows && k < K) v = A[(size_t)grow * K + k];
                sA[lkq + j][lrow] = v;
            }
#pragma unroll
            for (int j = 0; j < 4; ++j) {
                int k = kb + lkB;
                int n = colbase + lnB + j;
                sB[lkB][lnB + j] = (k < K) ? W[(size_t)k * HIDC + n] : 0.0f;
            }
            __syncthreads();
#pragma unroll
            for (int kk = 0; kk < BK; ++kk) {
                float a[4], b[4];
#pragma unroll
                for (int i = 0; i < 4; ++i) a[i] = sA[kk][ty * 4 + i];
#pragma unroll
                for (int j = 0; j < 4; ++j) b[j] = sB[kk][tx * 4 + j];
#pragma unroll
                for (int i = 0; i < 4; ++i)
#pragma unroll
                    for (int j = 0; j < 4; ++j) acc[i][j] += a[i] * b[j];
            }
            __syncthreads();
        }
    }
#pragma unroll
    for (int i = 0; i < 4; ++i) {
        int r = rowbase + ty * 4 + i;
        if (r >= nrows) continue;
#pragma unroll
        for (int j = 0; j < 4; ++j) {
            int c = colbase + tx * 4 + j;
            out[(size_t)r * HIDC + c] = f2bf(fmaxf(acc[i][j] + bias[c], 0.0f));
        }
    }
}

// ---------- MFMA bf16 SAGE GEMM (layers 2/3): out = relu(A0@B0 + A1@B1 + b) ----------
__global__ __launch_bounds__(256) void sage_gemm_mfma(
    const unsigned short* __restrict__ A0, const unsigned short* __restrict__ A1,
    const unsigned short* __restrict__ B0T, const unsigned short* __restrict__ B1T,
    const float* __restrict__ bias, unsigned short* __restrict__ out, int M) {
    constexpr int BM = 128, BK = 32, KD = 256, LDA = 40;
    __shared__ unsigned short sA[BM * LDA];
    __shared__ unsigned short sB[BM * LDA];
    const int tid = threadIdx.x;
    const int lane = tid & 63;
    const int wid = tid >> 6;
    const int wm = wid >> 1, wn = wid & 1;
    const int rowbase = blockIdx.x * BM, colbase = blockIdx.y * BM;

    const int fr = lane & 15;
    const int kq8 = (lane >> 4) << 3;

    f32x4 acc[4][4] = {};

    for (int pass = 0; pass < 2; ++pass) {
        const unsigned short* __restrict__ A = pass ? A1 : A0;
        const unsigned short* __restrict__ BT = pass ? B1T : B0T;
        for (int kb = 0; kb < KD; kb += BK) {
            int4 av[2], bv[2];
#pragma unroll
            for (int c = 0; c < 2; ++c) {
                int chunk = tid + (c << 8);
                int r = chunk >> 2, kq = (chunk & 3) << 3;
                int gr = rowbase + r;
                av[c] = (gr < M)
                            ? *reinterpret_cast<const int4*>(A + (size_t)gr * KD + kb + kq)
                            : make_int4(0, 0, 0, 0);
                bv[c] = *reinterpret_cast<const int4*>(BT + (size_t)(colbase + r) * KD + kb + kq);
            }
            __syncthreads();
#pragma unroll
            for (int c = 0; c < 2; ++c) {
                int chunk = tid + (c << 8);
                int r = chunk >> 2, kq = (chunk & 3) << 3;
                *reinterpret_cast<int4*>(sA + r * LDA + kq) = av[c];
                *reinterpret_cast<int4*>(sB + r * LDA + kq) = bv[c];
            }
            __syncthreads();
            bf16x8 af[4], bfr[4];
#pragma unroll
            for (int t = 0; t < 4; ++t) {
                af[t] = *reinterpret_cast<const bf16x8*>(sA + (wm * 64 + t * 16 + fr) * LDA + kq8);
                bfr[t] = *reinterpret_cast<const bf16x8*>(sB + (wn * 64 + t * 16 + fr) * LDA + kq8);
            }
#pragma unroll
            for (int i = 0; i < 4; ++i)
#pragma unroll
                for (int j = 0; j < 4; ++j)
                    acc[i][j] = __builtin_amdgcn_mfma_f32_16x16x32_bf16(af[i], bfr[j], acc[i][j], 0, 0, 0);
        }
    }

    const int crow0 = (lane >> 4) << 2;
#pragma unroll
    for (int i = 0; i < 4; ++i) {
#pragma unroll
        for (int j = 0; j < 4; ++j) {
            int col = colbase + wn * 64 + j * 16 + fr;
            float bb = bias[col];
#pragma unroll
            for (int r = 0; r < 4; ++r) {
                int row = rowbase + wm * 64 + i * 16 + crow0 + r;
                if (row < M)
                    out[(size_t)row * HIDC + col] = f2bf(fmaxf(acc[i][j][r] + bb, 0.0f));
            }
        }
    }
}

// ---------- segment-max pool ----------
__global__ void pool_max(const unsigned short* __restrict__ h, const int* __restrict__ gstart,
                         const int* __restrict__ gend, float* __restrict__ xc, int col_off) {
    int g = blockIdx.x;
    int c = threadIdx.x;
    float m = 0.0f;
    int s = gstart[g], e = gend[g];
    for (int i = s; i < e; ++i) m = fmaxf(m, bf2f(h[(size_t)i * HIDC + c]));
    xc[(size_t)g * (3 * HIDC) + col_off + c] = m;
}

// ---------- head MLPs ----------
__global__ void mlp1(const float* __restrict__ xc, const float* __restrict__ W,
                     const float* __restrict__ b, float* __restrict__ hmid) {
    __shared__ float row[3 * HIDC];
    int g = blockIdx.x;
    for (int i = threadIdx.x; i < 3 * HIDC; i += 256) row[i] = xc[(size_t)g * (3 * HIDC) + i];
    __syncthreads();
    float acc = b[threadIdx.x];
    for (int k = 0; k < 3 * HIDC; ++k) acc += row[k] * W[(size_t)k * HIDC + threadIdx.x];
    hmid[(size_t)g * HIDC + threadIdx.x] = fmaxf(acc, 0.0f);
}

__global__ void mlp2(const float* __restrict__ hmid, const float* __restrict__ W,
                     const float* __restrict__ b, float* __restrict__ out) {
    __shared__ float row[HIDC];
    int g = blockIdx.x;
    for (int i = threadIdx.x; i < HIDC; i += 128) row[i] = hmid[(size_t)g * HIDC + i];
    __syncthreads();
    float acc = b[threadIdx.x];
    for (int k = 0; k < HIDC; ++k) acc += row[k] * W[(size_t)k * OUT_DIMC + threadIdx.x];
    out[(size_t)g * OUT_DIMC + threadIdx.x] = acc;
}

static inline char* align_up(char* p, size_t a) {
    return (char*)(((uintptr_t)p + a - 1) & ~(uintptr_t)(a - 1));
}

extern "C" void kernel_launch(void* const* d_in, const int* in_sizes, int n_in,
                              void* d_out, int out_size, void* d_ws, size_t ws_size,
                              hipStream_t stream) {
    const float* x = (const float*)d_in[0];
    const int* edge_index = (const int*)d_in[1];
    const int* batch = (const int*)d_in[2];
    const float* W1l = (const float*)d_in[3];
    const float* W1r = (const float*)d_in[4];
    const float* b1 = (const float*)d_in[5];
    const float* W2l = (const float*)d_in[6];
    const float* W2r = (const float*)d_in[7];
    const float* b2 = (const float*)d_in[8];
    const float* W3l = (const float*)d_in[9];
    const float* W3r = (const float*)d_in[10];
    const float* b3 = (const float*)d_in[11];
    const float* Wlin1 = (const float*)d_in[12];
    const float* blin1 = (const float*)d_in[13];
    const float* Wlin2 = (const float*)d_in[14];
    const float* blin2 = (const float*)d_in[15];
    float* out = (float*)d_out;

    const int N = N_NODESC, E = N_EDGESC;
    const int* src = edge_index;
    const int* dst = edge_index + E;

    // ---- workspace carve-up ----
    char* w0 = (char*)d_ws;
    char* w = w0;
    int* cnt = (int*)w;        w = align_up(w + (size_t)N * 4, 256);
    float* invc = (float*)w;   w = align_up(w + (size_t)N * 4, 256);
    int* row_ofs = (int*)w;    w = align_up(w + (size_t)(N + 1) * 4, 256);
    int* bsum = (int*)w;       w = align_up(w + (size_t)SCAN_NBLK * 4, 256);
    int* csr = (int*)w;        w = align_up(w + (size_t)E * 4, 256);
    int* gstart = (int*)w;     w = align_up(w + (size_t)N_GRAPHSC * 4, 256);
    int* gend = (int*)w;       w = align_up(w + (size_t)N_GRAPHSC * 4, 256);
    float* xc = (float*)w;     w = align_up(w + (size_t)N_GRAPHSC * 3 * HIDC * 4, 256);
    float* hmid = (float*)w;   w = align_up(w + (size_t)N_GRAPHSC * HIDC * 4, 256);
    unsigned short* W2lT = (unsigned short*)w; w = align_up(w + (size_t)HIDC * HIDC * 2, 256);
    unsigned short* W2rT = (unsigned short*)w; w = align_up(w + (size_t)HIDC * HIDC * 2, 256);
    unsigned short* W3lT = (unsigned short*)w; w = align_up(w + (size_t)HIDC * HIDC * 2, 256);
    unsigned short* W3rT = (unsigned short*)w; w = align_up(w + (size_t)HIDC * HIDC * 2, 256);
    char* aggU = w;            w = align_up(w + (size_t)N * HIDC * 2, 256);
    unsigned short* h1 = (unsigned short*)w;  w = align_up(w + (size_t)N * HIDC * 2, 256);
    unsigned short* h2 = (unsigned short*)w;  w = align_up(w + (size_t)N * HIDC * 2, 256);
    size_t required = (size_t)(w - w0);
    if (ws_size < required) return;

    float* agg25 = (float*)aggU;
    unsigned short* aggH = (unsigned short*)aggU;

    const int nbN = (N + 255) / 256;
    const int nbE = (E + 255) / 256;
    const dim3 gemm_grid_f32((N + 63) / 64, HIDC / 64);
    const dim3 gemm_grid_mfma((N + 127) / 128, HIDC / 128);
    const dim3 tgrid(16, 16);

    // weight transposes
    wtransT<<<tgrid, 256, 0, stream>>>(W2l, W2lT);
    wtransT<<<tgrid, 256, 0, stream>>>(W2r, W2rT);
    wtransT<<<tgrid, 256, 0, stream>>>(W3l, W3lT);
    wtransT<<<tgrid, 256, 0, stream>>>(W3r, W3rT);

    // degrees + inv
    fill_u32<<<nbN, 256, 0, stream>>>((unsigned*)cnt, 0u, N);
    deg_kernel<<<nbE, 256, 0, stream>>>(dst, cnt, E);
    inv_kernel<<<nbN, 256, 0, stream>>>(cnt, invc, N);
    // CSR offsets: hierarchical scan
    scan_partial<<<SCAN_NBLK, SCAN_BLK, 0, stream>>>(cnt, row_ofs, bsum);
    scan_bsums<<<1, 128, 0, stream>>>(bsum);
    scan_add<<<SCAN_NBLK, SCAN_BLK, 0, stream>>>(row_ofs, bsum);
    fill_u32<<<nbN, 256, 0, stream>>>((unsigned*)cnt, 0u, N);
    csr_fill<<<nbE, 256, 0, stream>>>(src, dst, row_ofs, cnt, csr, E);
    // graph ranges: boundary scan (batch sorted, no atomics)
    fill_u32<<<1, 256, 0, stream>>>((unsigned*)gstart, (unsigned)N, N_GRAPHSC);
    fill_u32<<<1, 256, 0, stream>>>((unsigned*)gend, 0u, N_GRAPHSC);
    ranges_bounds<<<nbN, 256, 0, stream>>>(batch, gstart, gend, N);

    // ---- layer 1 (K=25, f32) ----
    gather25<<<(N * 32 + 255) / 256, 256, 0, stream>>>(x, row_ofs, csr, invc, agg25);
    sage_gemm_f32<IN_DIMC><<<gemm_grid_f32, 256, 0, stream>>>(agg25, x, W1l, W1r, b1, h1, N);
    pool_max<<<N_GRAPHSC, 256, 0, stream>>>(h1, gstart, gend, xc, 0);

    // ---- layer 2 (MFMA) ----
    gather256<<<(N * 64 + 255) / 256, 256, 0, stream>>>(h1, row_ofs, csr, invc, aggH);
    sage_gemm_mfma<<<gemm_grid_mfma, 256, 0, stream>>>(aggH, h1, W2lT, W2rT, b2, h2, N);
    pool_max<<<N_GRAPHSC, 256, 0, stream>>>(h2, gstart, gend, xc, HIDC);

    // ---- layer 3 (MFMA) ----
    gather256<<<(N * 64 + 255) / 256, 256, 0, stream>>>(h2, row_ofs, csr, invc, aggH);
    sage_gemm_mfma<<<gemm_grid_mfma, 256, 0, stream>>>(aggH, h2, W3lT, W3rT, b3, h1, N);
    pool_max<<<N_GRAPHSC, 256, 0, stream>>>(h1, gstart, gend, xc, 2 * HIDC);

    // ---- head ----
    mlp1<<<N_GRAPHSC, 256, 0, stream>>>(xc, Wlin1, blin1, hmid);
    mlp2<<<N_GRAPHSC, 128, 0, stream>>>(hmid, Wlin2, blin2, out);
}

// Round 6
// 1085.961 us; speedup vs baseline: 1.9314x; 1.1126x over previous
//
#include <hip/hip_runtime.h>
#include <hip/hip_bf16.h>

#define N_NODESC 100000
#define N_EDGESC 1600000
#define N_GRAPHSC 200
#define IN_DIMC 25
#define HIDC 256
#define OUT_DIMC 128
#define SCAN_BLK 1024
#define SCAN_NBLK ((N_NODESC + SCAN_BLK - 1) / SCAN_BLK)

typedef __attribute__((ext_vector_type(8))) short bf16x8;
typedef __attribute__((ext_vector_type(4))) float f32x4;

// ---------- bf16 helpers (raw ushort storage) ----------
__device__ inline float bf2f(unsigned short u) {
    union { float f; unsigned u32; } c;
    c.u32 = ((unsigned)u) << 16;
    return c.f;
}
__device__ inline unsigned short f2bf(float f) {
    union { float f; unsigned u; } c;
    c.f = f;
    unsigned r = (c.u + 0x7FFFu + ((c.u >> 16) & 1u)) >> 16;  // RNE
    return (unsigned short)r;
}
__device__ inline float u2f(unsigned u) {
    union { unsigned u; float f; } c;
    c.u = u;
    return c.f;
}

// ---------- utility fills ----------
__global__ void fill_u32(unsigned* __restrict__ p, unsigned v, int n) {
    int i = blockIdx.x * 256 + threadIdx.x;
    if (i < n) p[i] = v;
}

// ---------- degree / inv ----------
__global__ void deg_kernel(const int* __restrict__ dst, int* __restrict__ cnt, int E) {
    int i = blockIdx.x * 256 + threadIdx.x;
    if (i < E) atomicAdd(&cnt[dst[i]], 1);
}
__global__ void inv_kernel(const int* __restrict__ cnt, float* __restrict__ inv, int n) {
    int i = blockIdx.x * 256 + threadIdx.x;
    if (i < n) inv[i] = 1.0f / (float)max(cnt[i], 1);
}

// ---------- hierarchical exclusive scan over cnt[N] -> ofs[N+1] ----------
__global__ __launch_bounds__(SCAN_BLK) void scan_partial(const int* __restrict__ cnt,
                                                         int* __restrict__ ofs,
                                                         int* __restrict__ bsum) {
    __shared__ int sm[SCAN_BLK];
    int i = blockIdx.x * SCAN_BLK + threadIdx.x;
    int v = (i < N_NODESC) ? cnt[i] : 0;
    sm[threadIdx.x] = v;
    __syncthreads();
    for (int off = 1; off < SCAN_BLK; off <<= 1) {
        int t = (threadIdx.x >= off) ? sm[threadIdx.x - off] : 0;
        __syncthreads();
        sm[threadIdx.x] += t;
        __syncthreads();
    }
    if (i < N_NODESC) ofs[i] = sm[threadIdx.x] - v;  // exclusive within block
    if (threadIdx.x == SCAN_BLK - 1) bsum[blockIdx.x] = sm[SCAN_BLK - 1];
}

__global__ __launch_bounds__(128) void scan_bsums(int* __restrict__ bsum) {
    __shared__ int sm[SCAN_NBLK];
    if (threadIdx.x == 0) {
        int run = 0;
        for (int b = 0; b < SCAN_NBLK; ++b) {
            int t = bsum[b];
            sm[b] = run;
            run += t;
        }
        for (int b = 0; b < SCAN_NBLK; ++b) bsum[b] = sm[b];
    }
}

__global__ __launch_bounds__(SCAN_BLK) void scan_add(int* __restrict__ ofs,
                                                     const int* __restrict__ bsum) {
    int i = blockIdx.x * SCAN_BLK + threadIdx.x;
    if (i < N_NODESC) ofs[i] += bsum[blockIdx.x];
    if (i == 0) ofs[N_NODESC] = N_EDGESC;
}

// ---------- CSR fill ----------
__global__ void csr_fill(const int* __restrict__ src, const int* __restrict__ dst,
                         const int* __restrict__ ofs, int* __restrict__ cursor,
                         int* __restrict__ csr, int E) {
    int e = blockIdx.x * 256 + threadIdx.x;
    if (e < E) {
        int d = dst[e];
        int pos = atomicAdd(&cursor[d], 1);
        csr[ofs[d] + pos] = src[e];
    }
}

// ---------- graph ranges: boundary scan (batch sorted; no atomics) ----------
__global__ void ranges_bounds(const int* __restrict__ batch, int* __restrict__ gstart,
                              int* __restrict__ gend, int n) {
    int i = blockIdx.x * 256 + threadIdx.x;
    if (i >= n) return;
    int g = batch[i];
    if (i == 0 || batch[i - 1] != g) gstart[g] = i;
    if (i == n - 1 || batch[i + 1] != g) gend[g] = i + 1;
}

// ---------- weight transpose f32[256][256] -> bf16 WT[n][k] ----------
__global__ void wtransT(const float* __restrict__ W, unsigned short* __restrict__ WT) {
    __shared__ float t[16][17];
    int bx = blockIdx.x, by = blockIdx.y;
    int tx = threadIdx.x & 15, ty = threadIdx.x >> 4;
    t[ty][tx] = W[(by * 16 + ty) * HIDC + bx * 16 + tx];
    __syncthreads();
    WT[(size_t)(bx * 16 + ty) * HIDC + by * 16 + tx] = f2bf(t[tx][ty]);
}

// ---------- layer-1 mean gather (f32, 25 channels) ----------
__global__ void gather25(const float* __restrict__ x, const int* __restrict__ ofs,
                         const int* __restrict__ csr, const float* __restrict__ inv,
                         float* __restrict__ agg) {
    int idx = blockIdx.x * 256 + threadIdx.x;
    int node = idx >> 5, c = idx & 31;
    if (node >= N_NODESC || c >= IN_DIMC) return;
    float acc = 0.0f;
    int s = ofs[node], e = ofs[node + 1];
    for (int j = s; j < e; ++j) acc += x[(size_t)csr[j] * IN_DIMC + c];
    agg[(size_t)node * IN_DIMC + c] = acc * inv[node];
}

// ---------- hidden mean gather: one wave/node, half-wave/edge, 16B lanes ----------
__global__ void gather256(const unsigned short* __restrict__ h, const int* __restrict__ ofs,
                          const int* __restrict__ csr, const float* __restrict__ inv,
                          unsigned short* __restrict__ agg) {
    long long gtid = (long long)blockIdx.x * 256 + threadIdx.x;
    int node = (int)(gtid >> 6);
    if (node >= N_NODESC) return;
    const int lane = threadIdx.x & 63;
    const int half = lane >> 5;   // half-wave 0: even edges, 1: odd edges
    const int l = lane & 31;      // channel group: 8 bf16 = 16 B at l*8
    const int s = ofs[node], e = ofs[node + 1];

    float a0 = 0, a1 = 0, a2 = 0, a3 = 0, a4 = 0, a5 = 0, a6 = 0, a7 = 0;
    const size_t coff = (size_t)l * 8;

    int j = s + half;
    // unroll x2 per half-wave -> up to 4 independent 512B row reads in flight/wave
    for (; j + 2 < e; j += 4) {
        int sn0 = csr[j];
        int sn1 = csr[j + 2];
        int4 v0 = *reinterpret_cast<const int4*>(h + (size_t)sn0 * HIDC + coff);
        int4 v1 = *reinterpret_cast<const int4*>(h + (size_t)sn1 * HIDC + coff);
        a0 += u2f(((unsigned)v0.x) << 16); a1 += u2f(((unsigned)v0.x) & 0xffff0000u);
        a2 += u2f(((unsigned)v0.y) << 16); a3 += u2f(((unsigned)v0.y) & 0xffff0000u);
        a4 += u2f(((unsigned)v0.z) << 16); a5 += u2f(((unsigned)v0.z) & 0xffff0000u);
        a6 += u2f(((unsigned)v0.w) << 16); a7 += u2f(((unsigned)v0.w) & 0xffff0000u);
        a0 += u2f(((unsigned)v1.x) << 16); a1 += u2f(((unsigned)v1.x) & 0xffff0000u);
        a2 += u2f(((unsigned)v1.y) << 16); a3 += u2f(((unsigned)v1.y) & 0xffff0000u);
        a4 += u2f(((unsigned)v1.z) << 16); a5 += u2f(((unsigned)v1.z) & 0xffff0000u);
        a6 += u2f(((unsigned)v1.w) << 16); a7 += u2f(((unsigned)v1.w) & 0xffff0000u);
    }
    if (j < e) {
        int sn0 = csr[j];
        int4 v0 = *reinterpret_cast<const int4*>(h + (size_t)sn0 * HIDC + coff);
        a0 += u2f(((unsigned)v0.x) << 16); a1 += u2f(((unsigned)v0.x) & 0xffff0000u);
        a2 += u2f(((unsigned)v0.y) << 16); a3 += u2f(((unsigned)v0.y) & 0xffff0000u);
        a4 += u2f(((unsigned)v0.z) << 16); a5 += u2f(((unsigned)v0.z) & 0xffff0000u);
        a6 += u2f(((unsigned)v0.w) << 16); a7 += u2f(((unsigned)v0.w) & 0xffff0000u);
    }

    // combine halves (lane i <-> lane i+32)
    a0 += __shfl_xor(a0, 32, 64); a1 += __shfl_xor(a1, 32, 64);
    a2 += __shfl_xor(a2, 32, 64); a3 += __shfl_xor(a3, 32, 64);
    a4 += __shfl_xor(a4, 32, 64); a5 += __shfl_xor(a5, 32, 64);
    a6 += __shfl_xor(a6, 32, 64); a7 += __shfl_xor(a7, 32, 64);

    if (half == 0) {
        float sc = inv[node];
        int4 p;
        p.x = (int)((unsigned)f2bf(a0 * sc) | ((unsigned)f2bf(a1 * sc) << 16));
        p.y = (int)((unsigned)f2bf(a2 * sc) | ((unsigned)f2bf(a3 * sc) << 16));
        p.z = (int)((unsigned)f2bf(a4 * sc) | ((unsigned)f2bf(a5 * sc) << 16));
        p.w = (int)((unsigned)f2bf(a6 * sc) | ((unsigned)f2bf(a7 * sc) << 16));
        *reinterpret_cast<int4*>(agg + (size_t)node * HIDC + coff) = p;
    }
}

// ---------- layer-1 f32 SAGE GEMM (K=25) ----------
template <int K>
__global__ __launch_bounds__(256) void sage_gemm_f32(
    const float* __restrict__ agg, const float* __restrict__ h,
    const float* __restrict__ Wl, const float* __restrict__ Wr,
    const float* __restrict__ bias,
    unsigned short* __restrict__ out, int nrows) {
    constexpr int BM = 64, BN = 64, BK = 16;
    __shared__ float sA[BK][BM + 4];
    __shared__ float sB[BK][BN + 4];
    const int tid = threadIdx.x;
    const int tx = tid & 15, ty = tid >> 4;
    const int rowbase = blockIdx.x * BM;
    const int colbase = blockIdx.y * BN;
    float acc[4][4] = {};
    const int lrow = tid >> 2, lkq = (tid & 3) * 4;
    const int lkB = tid >> 4, lnB = (tid & 15) * 4;

    for (int pass = 0; pass < 2; ++pass) {
        const float* __restrict__ A = pass ? h : agg;
        const float* __restrict__ W = pass ? Wr : Wl;
        const int grow = rowbase + lrow;
        for (int kb = 0; kb < K; kb += BK) {
#pragma unroll
            for (int j = 0; j < 4; ++j) {
                int k = kb + lkq + j;
                float v = 0.0f;
                if (grow < nrows && k < K) v = A[(size_t)grow * K + k];
                sA[lkq + j][lrow] = v;
            }
#pragma unroll
            for (int j = 0; j < 4; ++j) {
                int k = kb + lkB;
                int n = colbase + lnB + j;
                sB[lkB][lnB + j] = (k < K) ? W[(size_t)k * HIDC + n] : 0.0f;
            }
            __syncthreads();
#pragma unroll
            for (int kk = 0; kk < BK; ++kk) {
                float a[4], b[4];
#pragma unroll
                for (int i = 0; i < 4; ++i) a[i] = sA[kk][ty * 4 + i];
#pragma unroll
                for (int j = 0; j < 4; ++j) b[j] = sB[kk][tx * 4 + j];
#pragma unroll
                for (int i = 0; i < 4; ++i)
#pragma unroll
                    for (int j = 0; j < 4; ++j) acc[i][j] += a[i] * b[j];
            }
            __syncthreads();
        }
    }
#pragma unroll
    for (int i = 0; i < 4; ++i) {
        int r = rowbase + ty * 4 + i;
        if (r >= nrows) continue;
#pragma unroll
        for (int j = 0; j < 4; ++j) {
            int c = colbase + tx * 4 + j;
            out[(size_t)r * HIDC + c] = f2bf(fmaxf(acc[i][j] + bias[c], 0.0f));
        }
    }
}

// ---------- MFMA bf16 SAGE GEMM (layers 2/3): out = relu(A0@B0 + A1@B1 + b) ----------
__global__ __launch_bounds__(256) void sage_gemm_mfma(
    const unsigned short* __restrict__ A0, const unsigned short* __restrict__ A1,
    const unsigned short* __restrict__ B0T, const unsigned short* __restrict__ B1T,
    const float* __restrict__ bias, unsigned short* __restrict__ out, int M) {
    constexpr int BM = 128, BK = 32, KD = 256, LDA = 40;
    __shared__ unsigned short sA[BM * LDA];
    __shared__ unsigned short sB[BM * LDA];
    const int tid = threadIdx.x;
    const int lane = tid & 63;
    const int wid = tid >> 6;
    const int wm = wid >> 1, wn = wid & 1;
    const int rowbase = blockIdx.x * BM, colbase = blockIdx.y * BM;

    const int fr = lane & 15;
    const int kq8 = (lane >> 4) << 3;

    f32x4 acc[4][4] = {};

    for (int pass = 0; pass < 2; ++pass) {
        const unsigned short* __restrict__ A = pass ? A1 : A0;
        const unsigned short* __restrict__ BT = pass ? B1T : B0T;
        for (int kb = 0; kb < KD; kb += BK) {
            int4 av[2], bv[2];
#pragma unroll
            for (int c = 0; c < 2; ++c) {
                int chunk = tid + (c << 8);
                int r = chunk >> 2, kq = (chunk & 3) << 3;
                int gr = rowbase + r;
                av[c] = (gr < M)
                            ? *reinterpret_cast<const int4*>(A + (size_t)gr * KD + kb + kq)
                            : make_int4(0, 0, 0, 0);
                bv[c] = *reinterpret_cast<const int4*>(BT + (size_t)(colbase + r) * KD + kb + kq);
            }
            __syncthreads();
#pragma unroll
            for (int c = 0; c < 2; ++c) {
                int chunk = tid + (c << 8);
                int r = chunk >> 2, kq = (chunk & 3) << 3;
                *reinterpret_cast<int4*>(sA + r * LDA + kq) = av[c];
                *reinterpret_cast<int4*>(sB + r * LDA + kq) = bv[c];
            }
            __syncthreads();
            bf16x8 af[4], bfr[4];
#pragma unroll
            for (int t = 0; t < 4; ++t) {
                af[t] = *reinterpret_cast<const bf16x8*>(sA + (wm * 64 + t * 16 + fr) * LDA + kq8);
                bfr[t] = *reinterpret_cast<const bf16x8*>(sB + (wn * 64 + t * 16 + fr) * LDA + kq8);
            }
#pragma unroll
            for (int i = 0; i < 4; ++i)
#pragma unroll
                for (int j = 0; j < 4; ++j)
                    acc[i][j] = __builtin_amdgcn_mfma_f32_16x16x32_bf16(af[i], bfr[j], acc[i][j], 0, 0, 0);
        }
    }

    const int crow0 = (lane >> 4) << 2;
#pragma unroll
    for (int i = 0; i < 4; ++i) {
#pragma unroll
        for (int j = 0; j < 4; ++j) {
            int col = colbase + wn * 64 + j * 16 + fr;
            float bb = bias[col];
#pragma unroll
            for (int r = 0; r < 4; ++r) {
                int row = rowbase + wm * 64 + i * 16 + crow0 + r;
                if (row < M)
                    out[(size_t)row * HIDC + col] = f2bf(fmaxf(acc[i][j][r] + bb, 0.0f));
            }
        }
    }
}

// ---------- segment-max pool ----------
__global__ void pool_max(const unsigned short* __restrict__ h, const int* __restrict__ gstart,
                         const int* __restrict__ gend, float* __restrict__ xc, int col_off) {
    int g = blockIdx.x;
    int c = threadIdx.x;
    float m = 0.0f;
    int s = gstart[g], e = gend[g];
    for (int i = s; i < e; ++i) m = fmaxf(m, bf2f(h[(size_t)i * HIDC + c]));
    xc[(size_t)g * (3 * HIDC) + col_off + c] = m;
}

// ---------- head MLPs ----------
__global__ void mlp1(const float* __restrict__ xc, const float* __restrict__ W,
                     const float* __restrict__ b, float* __restrict__ hmid) {
    __shared__ float row[3 * HIDC];
    int g = blockIdx.x;
    for (int i = threadIdx.x; i < 3 * HIDC; i += 256) row[i] = xc[(size_t)g * (3 * HIDC) + i];
    __syncthreads();
    float acc = b[threadIdx.x];
    for (int k = 0; k < 3 * HIDC; ++k) acc += row[k] * W[(size_t)k * HIDC + threadIdx.x];
    hmid[(size_t)g * HIDC + threadIdx.x] = fmaxf(acc, 0.0f);
}

__global__ void mlp2(const float* __restrict__ hmid, const float* __restrict__ W,
                     const float* __restrict__ b, float* __restrict__ out) {
    __shared__ float row[HIDC];
    int g = blockIdx.x;
    for (int i = threadIdx.x; i < HIDC; i += 128) row[i] = hmid[(size_t)g * HIDC + i];
    __syncthreads();
    float acc = b[threadIdx.x];
    for (int k = 0; k < HIDC; ++k) acc += row[k] * W[(size_t)k * OUT_DIMC + threadIdx.x];
    out[(size_t)g * OUT_DIMC + threadIdx.x] = acc;
}

static inline char* align_up(char* p, size_t a) {
    return (char*)(((uintptr_t)p + a - 1) & ~(uintptr_t)(a - 1));
}

extern "C" void kernel_launch(void* const* d_in, const int* in_sizes, int n_in,
                              void* d_out, int out_size, void* d_ws, size_t ws_size,
                              hipStream_t stream) {
    const float* x = (const float*)d_in[0];
    const int* edge_index = (const int*)d_in[1];
    const int* batch = (const int*)d_in[2];
    const float* W1l = (const float*)d_in[3];
    const float* W1r = (const float*)d_in[4];
    const float* b1 = (const float*)d_in[5];
    const float* W2l = (const float*)d_in[6];
    const float* W2r = (const float*)d_in[7];
    const float* b2 = (const float*)d_in[8];
    const float* W3l = (const float*)d_in[9];
    const float* W3r = (const float*)d_in[10];
    const float* b3 = (const float*)d_in[11];
    const float* Wlin1 = (const float*)d_in[12];
    const float* blin1 = (const float*)d_in[13];
    const float* Wlin2 = (const float*)d_in[14];
    const float* blin2 = (const float*)d_in[15];
    float* out = (float*)d_out;

    const int N = N_NODESC, E = N_EDGESC;
    const int* src = edge_index;
    const int* dst = edge_index + E;

    // ---- workspace carve-up ----
    char* w0 = (char*)d_ws;
    char* w = w0;
    int* cnt = (int*)w;        w = align_up(w + (size_t)N * 4, 256);
    float* invc = (float*)w;   w = align_up(w + (size_t)N * 4, 256);
    int* row_ofs = (int*)w;    w = align_up(w + (size_t)(N + 1) * 4, 256);
    int* bsum = (int*)w;       w = align_up(w + (size_t)SCAN_NBLK * 4, 256);
    int* csr = (int*)w;        w = align_up(w + (size_t)E * 4, 256);
    int* gstart = (int*)w;     w = align_up(w + (size_t)N_GRAPHSC * 4, 256);
    int* gend = (int*)w;       w = align_up(w + (size_t)N_GRAPHSC * 4, 256);
    float* xc = (float*)w;     w = align_up(w + (size_t)N_GRAPHSC * 3 * HIDC * 4, 256);
    float* hmid = (float*)w;   w = align_up(w + (size_t)N_GRAPHSC * HIDC * 4, 256);
    unsigned short* W2lT = (unsigned short*)w; w = align_up(w + (size_t)HIDC * HIDC * 2, 256);
    unsigned short* W2rT = (unsigned short*)w; w = align_up(w + (size_t)HIDC * HIDC * 2, 256);
    unsigned short* W3lT = (unsigned short*)w; w = align_up(w + (size_t)HIDC * HIDC * 2, 256);
    unsigned short* W3rT = (unsigned short*)w; w = align_up(w + (size_t)HIDC * HIDC * 2, 256);
    char* aggU = w;            w = align_up(w + (size_t)N * HIDC * 2, 256);
    unsigned short* h1 = (unsigned short*)w;  w = align_up(w + (size_t)N * HIDC * 2, 256);
    unsigned short* h2 = (unsigned short*)w;  w = align_up(w + (size_t)N * HIDC * 2, 256);
    size_t required = (size_t)(w - w0);
    if (ws_size < required) return;

    float* agg25 = (float*)aggU;
    unsigned short* aggH = (unsigned short*)aggU;

    const int nbN = (N + 255) / 256;
    const int nbE = (E + 255) / 256;
    const dim3 gemm_grid_f32((N + 63) / 64, HIDC / 64);
    const dim3 gemm_grid_mfma((N + 127) / 128, HIDC / 128);
    const dim3 tgrid(16, 16);

    // weight transposes
    wtransT<<<tgrid, 256, 0, stream>>>(W2l, W2lT);
    wtransT<<<tgrid, 256, 0, stream>>>(W2r, W2rT);
    wtransT<<<tgrid, 256, 0, stream>>>(W3l, W3lT);
    wtransT<<<tgrid, 256, 0, stream>>>(W3r, W3rT);

    // degrees + inv
    fill_u32<<<nbN, 256, 0, stream>>>((unsigned*)cnt, 0u, N);
    deg_kernel<<<nbE, 256, 0, stream>>>(dst, cnt, E);
    inv_kernel<<<nbN, 256, 0, stream>>>(cnt, invc, N);
    // CSR offsets: hierarchical scan
    scan_partial<<<SCAN_NBLK, SCAN_BLK, 0, stream>>>(cnt, row_ofs, bsum);
    scan_bsums<<<1, 128, 0, stream>>>(bsum);
    scan_add<<<SCAN_NBLK, SCAN_BLK, 0, stream>>>(row_ofs, bsum);
    fill_u32<<<nbN, 256, 0, stream>>>((unsigned*)cnt, 0u, N);
    csr_fill<<<nbE, 256, 0, stream>>>(src, dst, row_ofs, cnt, csr, E);
    // graph ranges
    fill_u32<<<1, 256, 0, stream>>>((unsigned*)gstart, (unsigned)N, N_GRAPHSC);
    fill_u32<<<1, 256, 0, stream>>>((unsigned*)gend, 0u, N_GRAPHSC);
    ranges_bounds<<<nbN, 256, 0, stream>>>(batch, gstart, gend, N);

    // ---- layer 1 (K=25, f32) ----
    gather25<<<(N * 32 + 255) / 256, 256, 0, stream>>>(x, row_ofs, csr, invc, agg25);
    sage_gemm_f32<IN_DIMC><<<gemm_grid_f32, 256, 0, stream>>>(agg25, x, W1l, W1r, b1, h1, N);
    pool_max<<<N_GRAPHSC, 256, 0, stream>>>(h1, gstart, gend, xc, 0);

    // ---- layer 2 (MFMA) ----
    gather256<<<(N * 64 + 255) / 256, 256, 0, stream>>>(h1, row_ofs, csr, invc, aggH);
    sage_gemm_mfma<<<gemm_grid_mfma, 256, 0, stream>>>(aggH, h1, W2lT, W2rT, b2, h2, N);
    pool_max<<<N_GRAPHSC, 256, 0, stream>>>(h2, gstart, gend, xc, HIDC);

    // ---- layer 3 (MFMA) ----
    gather256<<<(N * 64 + 255) / 256, 256, 0, stream>>>(h2, row_ofs, csr, invc, aggH);
    sage_gemm_mfma<<<gemm_grid_mfma, 256, 0, stream>>>(aggH, h2, W3lT, W3rT, b3, h1, N);
    pool_max<<<N_GRAPHSC, 256, 0, stream>>>(h1, gstart, gend, xc, 2 * HIDC);

    // ---- head ----
    mlp1<<<N_GRAPHSC, 256, 0, stream>>>(xc, Wlin1, blin1, hmid);
    mlp2<<<N_GRAPHSC, 128, 0, stream>>>(hmid, Wlin2, blin2, out);
}